// Round 4
// baseline (107.667 us; speedup 1.0000x reference)
//
#include <hip/hip_runtime.h>
#include <hip/hip_bf16.h>
#include <stdint.h>

typedef short bf16x8 __attribute__((ext_vector_type(8)));
typedef short short8 __attribute__((ext_vector_type(8)));
typedef float f32x4 __attribute__((ext_vector_type(4)));

#define B_   64
#define NQ   32
#define ND   256
#define DIM  128
#define MT   4          // bq values per chamfer block
#define NEG_INF_F (-1.0e9f)
#define VALID_F   (-1.0e8f)

// dn global layout is PRE-SWIZZLED: 16B chunk j of row r lives at chunk j ^ (r&7)
// (m173 pattern: pre-swizzled global + linear global_load_lds + swizzled ds_read
//  => conflict-free b128 LDS reads). qn is LINEAR (read directly from global).

__device__ __forceinline__ void lds_cp16(const void* g, void* l) {
    __builtin_amdgcn_global_load_lds(
        (const __attribute__((address_space(1))) unsigned int*)g,
        (__attribute__((address_space(3))) unsigned int*)l,
        16, 0, 0);
}

// ---------------- Kernel 1: L2-normalize rows, mask, emit bf16 ----------------
// 16 lanes per row. Q rows stored linear; D rows stored swizzled.
__global__ __launch_bounds__(256) void normalize_rows(
    const float* __restrict__ q, const int* __restrict__ qmask,
    const float* __restrict__ d, const int* __restrict__ dmask,
    __hip_bfloat16* __restrict__ qn, __hip_bfloat16* __restrict__ dn)
{
    const int tid  = threadIdx.x;
    const int sub  = tid & 15;
    const int row  = blockIdx.x * 16 + (tid >> 4);   // 0 .. 18431

    const float* src;
    __hip_bfloat16* dst;
    int m, swz;
    if (row < B_ * NQ) {
        src = q + (size_t)row * DIM;  dst = qn + (size_t)row * DIM;
        m = qmask[row];  swz = 0;
    } else {
        const int r2 = row - B_ * NQ;
        src = d + (size_t)r2 * DIM;   dst = dn + (size_t)r2 * DIM;
        m = dmask[r2];   swz = r2 & 7;
    }

    const float4 v0 = *reinterpret_cast<const float4*>(src + sub * 8);
    const float4 v1 = *reinterpret_cast<const float4*>(src + sub * 8 + 4);
    float ss = v0.x*v0.x + v0.y*v0.y + v0.z*v0.z + v0.w*v0.w
             + v1.x*v1.x + v1.y*v1.y + v1.z*v1.z + v1.w*v1.w;
    #pragma unroll
    for (int off = 1; off <= 8; off <<= 1) ss += __shfl_xor(ss, off);

    const float scale = m ? (1.0f / fmaxf(sqrtf(ss), 1e-12f)) : 0.0f;

    short8 o;
    const float f[8] = {v0.x, v0.y, v0.z, v0.w, v1.x, v1.y, v1.z, v1.w};
    #pragma unroll
    for (int j = 0; j < 8; ++j) {
        __hip_bfloat16 b = __float2bfloat16(f[j] * scale);
        o[j] = *reinterpret_cast<short*>(&b);
    }
    *reinterpret_cast<short8*>(dst + (sub ^ swz) * 8) = o;
}

// ---------------- Kernel 2: (4 bq, bd) MFMA tile + chamfer reductions ------
// LDS = D panel (64KB, global_load_lds staged) + reduce buffers (~6KB) => 70KB
// => 2 blocks/CU: one block's staging overlaps the other's compute.
// Q fragments read straight from global (L2-resident, identical across waves).
// MFMA 16x16x32 bf16: A lane row=l&15, k=(l>>4)*8+j; C/D col=l&15, row=(l>>4)*4+reg.
// Mask quirk: pair (bq,bd) gated by qm[bq,t] && dm[bq,s] (doc mask via QUERY batch).
__global__ __launch_bounds__(256) void chamfer_main(
    const __hip_bfloat16* __restrict__ qn,
    const __hip_bfloat16* __restrict__ dn,
    const int* __restrict__ qmask,
    const int* __restrict__ dmask,
    float* __restrict__ out)
{
    __shared__ __hip_bfloat16 ldsD[ND * DIM];        // 64 KB
    __shared__ float s_cmax[MT][ND];                 // 4 KB
    __shared__ float s_rmaxT[MT][NQ][4];             // 2 KB

    const int bq0 = (blockIdx.x >> 6) * MT;
    const int bd  = blockIdx.x & 63;
    const int tid = threadIdx.x;
    const int w   = tid >> 6;
    const int l   = tid & 63;
    const int lr  = l & 15;
    const int lk  = l >> 4;

    // ---- stage D: wave w copies its 16KB slice (16 back-to-back 1KB issues) ----
    {
        const char* gD = (const char*)(dn + (size_t)(bd * ND) * DIM) + w * 16384;
        char*       lD = (char*)&ldsD[0] + w * 16384;
        #pragma unroll
        for (int c = 0; c < 16; ++c)
            lds_cp16(gD + c * 1024 + l * 16, lD + c * 1024);
    }

    // ---- masks into registers (overlap staging) — doc mask indexed by bq (quirk)
    int qmv[MT][2][4];
    int dmv[MT][4];
    #pragma unroll
    for (int m = 0; m < MT; ++m) {
        #pragma unroll
        for (int mi = 0; mi < 2; ++mi)
            #pragma unroll
            for (int r = 0; r < 4; ++r)
                qmv[m][mi][r] = qmask[(bq0 + m) * NQ + mi * 16 + lk * 4 + r];
        #pragma unroll
        for (int ni = 0; ni < 4; ++ni)
            dmv[m][ni] = dmask[(bq0 + m) * ND + w * 64 + ni * 16 + lr];
    }

    __syncthreads();   // drains vmcnt (global_load_lds)

    // ---- MFMA phase: B-frags from LDS (swizzled), A-frags from global ----
    f32x4 acc[MT][2][4] = {};
    __builtin_amdgcn_s_setprio(1);
    #pragma unroll
    for (int kk = 0; kk < 4; ++kk) {
        const int k0   = kk * 32 + lk * 8;
        const int slot = (kk * 4 + lk) ^ (lr & 7);
        bf16x8 bfr[4];
        #pragma unroll
        for (int ni = 0; ni < 4; ++ni) {
            const int rowd = w * 64 + ni * 16 + lr;
            bfr[ni] = *reinterpret_cast<const bf16x8*>((const char*)&ldsD[0] + rowd * 256 + slot * 16);
        }
        #pragma unroll
        for (int m = 0; m < MT; ++m) {
            const __hip_bfloat16* Q = qn + (size_t)(bq0 + m) * (NQ * DIM);
            #pragma unroll
            for (int mi = 0; mi < 2; ++mi) {
                const bf16x8 a = *reinterpret_cast<const bf16x8*>(Q + (mi * 16 + lr) * DIM + k0);
                #pragma unroll
                for (int ni = 0; ni < 4; ++ni)
                    acc[m][mi][ni] = __builtin_amdgcn_mfma_f32_16x16x32_bf16(a, bfr[ni], acc[m][mi][ni], 0, 0, 0);
            }
        }
    }
    __builtin_amdgcn_s_setprio(0);

    // ---- per-wave partial maxes → LDS (2-step + 4-step shuffles only) ----
    #pragma unroll
    for (int m = 0; m < MT; ++m) {
        float rmax[2][4];
        float cmax[4];
        #pragma unroll
        for (int ni = 0; ni < 4; ++ni) cmax[ni] = NEG_INF_F;
        #pragma unroll
        for (int mi = 0; mi < 2; ++mi) {
            #pragma unroll
            for (int r = 0; r < 4; ++r) {
                float rm = NEG_INF_F;
                #pragma unroll
                for (int ni = 0; ni < 4; ++ni) {
                    const float v = (qmv[m][mi][r] && dmv[m][ni]) ? acc[m][mi][ni][r] : NEG_INF_F;
                    rm = fmaxf(rm, v);
                    cmax[ni] = fmaxf(cmax[ni], v);
                }
                rmax[mi][r] = rm;
            }
        }
        // column max over 32 rows (lanes differing in lk bits)
        #pragma unroll
        for (int ni = 0; ni < 4; ++ni) {
            cmax[ni] = fmaxf(cmax[ni], __shfl_xor(cmax[ni], 16));
            cmax[ni] = fmaxf(cmax[ni], __shfl_xor(cmax[ni], 32));
        }
        if (lk == 0) {
            #pragma unroll
            for (int ni = 0; ni < 4; ++ni)
                s_cmax[m][w * 64 + ni * 16 + lr] = cmax[ni];
        }
        // row max over this wave's 64 cols (lanes differing in lr bits)
        #pragma unroll
        for (int mi = 0; mi < 2; ++mi)
            #pragma unroll
            for (int r = 0; r < 4; ++r) {
                #pragma unroll
                for (int off = 1; off <= 8; off <<= 1)
                    rmax[mi][r] = fmaxf(rmax[mi][r], __shfl_xor(rmax[mi][r], off));
            }
        if (lr == 0) {
            #pragma unroll
            for (int mi = 0; mi < 2; ++mi)
                #pragma unroll
                for (int r = 0; r < 4; ++r)
                    s_rmaxT[m][mi * 16 + lk * 4 + r][w] = rmax[mi][r];
        }
    }
    __syncthreads();

    // ---- final combine: wave w finishes bq index m = w ----
    {
        const int m = w;
        const float4 cm = *reinterpret_cast<const float4*>(&s_cmax[m][l * 4]);
        float sd = 0.0f, cd = 0.0f;
        if (cm.x > VALID_F) { sd += cm.x; cd += 1.0f; }
        if (cm.y > VALID_F) { sd += cm.y; cd += 1.0f; }
        if (cm.z > VALID_F) { sd += cm.z; cd += 1.0f; }
        if (cm.w > VALID_F) { sd += cm.w; cd += 1.0f; }
        float sq = 0.0f, cq = 0.0f;
        if (l < NQ) {
            const float4 rm4 = *reinterpret_cast<const float4*>(&s_rmaxT[m][l][0]);
            const float v = fmaxf(fmaxf(rm4.x, rm4.y), fmaxf(rm4.z, rm4.w));
            if (v > VALID_F) { sq = v; cq = 1.0f; }
        }
        #pragma unroll
        for (int off = 1; off <= 32; off <<= 1) {
            sd += __shfl_xor(sd, off);
            cd += __shfl_xor(cd, off);
            sq += __shfl_xor(sq, off);
            cq += __shfl_xor(cq, off);
        }
        if (l == 0) {
            const float q2d = sq / fmaxf(cq, 1.0f);
            const float d2q = sd / fmaxf(cd, 1.0f);
            out[(bq0 + m) * B_ + bd] = 0.5f * (q2d + d2q);
        }
    }
}

extern "C" void kernel_launch(void* const* d_in, const int* in_sizes, int n_in,
                              void* d_out, int out_size, void* d_ws, size_t ws_size,
                              hipStream_t stream) {
    const float* q  = (const float*)d_in[0];   // [64][32][128] f32
    const int*   qm = (const int*)d_in[1];     // [64][32] i32
    const float* d  = (const float*)d_in[2];   // [64][256][128] f32
    const int*   dm = (const int*)d_in[3];     // [64][256] i32
    float* out = (float*)d_out;                // [64][64] f32

    __hip_bfloat16* qn = (__hip_bfloat16*)d_ws;          // 2048*128 bf16, linear
    __hip_bfloat16* dn = qn + (B_ * NQ) * DIM;           // 16384*128 bf16, swizzled

    normalize_rows<<<(B_ * NQ + B_ * ND) / 16, 256, 0, stream>>>(q, qm, d, dm, qn, dn);
    chamfer_main<<<(B_ / MT) * B_, 256, 0, stream>>>(qn, dn, qm, dm, out);
}